// Round 1
// baseline (1222.140 us; speedup 1.0000x reference)
//
#include <hip/hip_runtime.h>
#include <math.h>

#define GGRP 8
#define NPTS 8192
#define NG   1024      // points per group
#define BB   4
#define FF   64
#define CH   11
#define KF   192       // feature dim F*3
#define NGB  32        // G*B
#define KNN  16

// ws offsets in FLOATS
#define OFF_ORD_E  0        // 8192 int
#define OFF_ORD_A  8192     // 8192 int
#define OFF_BG_E   16384    // 8192 int
#define OFF_BG_A   24576    // 8192 int
#define OFF_MEAN_E 33024    // 96 f
#define OFF_MEAN_A 33152    // 96 f
#define OFF_STD_E  33280    // 2048 f
#define OFF_STD_A  35328    // 2048 f
#define OFF_PART   40960    // 8192*3 f
#define OFF_NORMS  65536    // 6*32*1024 f
#define OFF_MAT    262144
#define MATSZ      6291456  // 32*192*1024
#define OFF_D      38010880 // OFF_MAT + 6*MATSZ
// matrix order: 0 PE, 1 PA, 2 VE, 3 VA, 4 NPE, 5 NPA

__global__ void k_bg(const float* __restrict__ ex, const float* __restrict__ ac, float* ws) {
    int n = blockIdx.x * blockDim.x + threadIdx.x;
    if (n >= NPTS) return;
    int* bg_e = (int*)ws + OFF_BG_E;
    int* bg_a = (int*)ws + OFF_BG_A;
    const float* pe = ex + (size_t)n * CH + 3;
    const float* pa = ac + (size_t)n * CH + 3;
    float m = -1e30f; int a = 0;
    for (int c = 0; c < GGRP; c++) { float v = pe[c]; if (v > m) { m = v; a = c; } }
    bg_e[n] = a;
    m = -1e30f; a = 0;
    for (int c = 0; c < GGRP; c++) { float v = pa[c]; if (v > m) { m = v; a = c; } }
    bg_a[n] = a;
}

// stable counting-compaction: 16 waves, wave w<8 -> expected group w, w>=8 -> actual group w-8
__global__ void k_order(float* ws) {
    int tid = threadIdx.x;
    int w = tid >> 6, lane = tid & 63;
    const int* bg = (const int*)ws + ((w < 8) ? OFF_BG_E : OFF_BG_A);
    int* ord = (int*)ws + ((w < 8) ? OFF_ORD_E : OFF_ORD_A);
    int grp = w & 7;
    __shared__ int cnts[16];
    int cnt = 0;
    for (int base = 0; base < NPTS; base += 64) {
        int v = bg[base + lane];
        unsigned long long m = __ballot(v == grp);
        cnt += __popcll(m);
    }
    if (lane == 0) cnts[w] = cnt;
    __syncthreads();
    int pos = 0;
    for (int g2 = 0; g2 < grp; g2++) pos += cnts[(w & 8) | g2];
    for (int base = 0; base < NPTS; base += 64) {
        int v = bg[base + lane];
        unsigned long long m = __ballot(v == grp);
        int pre = __popcll(m & ((1ull << lane) - 1ull));
        if (v == grp) { int slot = pos + pre; if (slot < NPTS) ord[slot] = base + lane; }
        pos += __popcll(m);
    }
}

// build PE_T / PA_T : layout [gb][k=f*3+c][i]
__global__ void k_gather(const float* __restrict__ ex, const float* __restrict__ ac, float* ws) {
    int f = blockIdx.x, gb = blockIdx.y;
    int g = gb >> 2, b = gb & 3;
    const int* ord_e = (const int*)ws + OFF_ORD_E;
    const int* ord_a = (const int*)ws + OFF_ORD_A;
    float* PE = ws + OFF_MAT;
    float* PA = ws + OFF_MAT + (size_t)1 * MATSZ;
    size_t mbase = ((size_t)gb * KF + f * 3) * NG;
    size_t sbase = ((size_t)(b * FF + f)) * NPTS;
    for (int i = threadIdx.x; i < NG; i += blockDim.x) {
        int ne = ord_e[g * NG + i];
        const float* p = ex + (sbase + ne) * CH;
        PE[mbase + i] = p[0]; PE[mbase + NG + i] = p[1]; PE[mbase + 2 * NG + i] = p[2];
        int na = ord_a[g * NG + i];
        const float* q = ac + (sbase + na) * CH;
        PA[mbase + i] = q[0]; PA[mbase + NG + i] = q[1]; PA[mbase + 2 * NG + i] = q[2];
    }
}

__global__ void k_mean(float* ws) {
    int gb = blockIdx.x, side = blockIdx.y;
    const float* M = ws + OFF_MAT + (size_t)side * MATSZ + (size_t)gb * KF * NG;
    float* mean = ws + (side ? OFF_MEAN_A : OFF_MEAN_E) + gb * 3;
    float s0 = 0, s1 = 0, s2 = 0;
    for (int idx = threadIdx.x; idx < KF * NG; idx += 256) {
        int k = idx >> 10; int c = k % 3;
        float v = M[idx];
        if (c == 0) s0 += v; else if (c == 1) s1 += v; else s2 += v;
    }
    __shared__ float red[256];
    for (int c = 0; c < 3; c++) {
        float s = (c == 0) ? s0 : ((c == 1) ? s1 : s2);
        red[threadIdx.x] = s; __syncthreads();
        for (int off = 128; off; off >>= 1) { if (threadIdx.x < off) red[threadIdx.x] += red[threadIdx.x + off]; __syncthreads(); }
        if (threadIdx.x == 0) mean[c] = red[0] / (float)(FF * NG);
        __syncthreads();
    }
}

// std over (n,3) of centered data, ddof=1, WITH its own mean subtraction (two-sum form)
__global__ void k_std(float* ws) {
    int gb = blockIdx.x, f = blockIdx.y, side = blockIdx.z;
    const float* M = ws + OFF_MAT + (size_t)side * MATSZ + ((size_t)gb * KF + f * 3) * NG;
    const float* mean = ws + (side ? OFF_MEAN_A : OFF_MEAN_E) + gb * 3;
    float m0 = mean[0], m1 = mean[1], m2 = mean[2];
    float s2 = 0, s1 = 0;
    for (int idx = threadIdx.x; idx < 3 * NG; idx += 128) {
        int c = idx >> 10;
        float mm = (c == 0) ? m0 : ((c == 1) ? m1 : m2);
        float v = M[idx] - mm;
        s1 += v; s2 += v * v;
    }
    __shared__ float redA[128], redB[128];
    redA[threadIdx.x] = s1; redB[threadIdx.x] = s2; __syncthreads();
    for (int off = 64; off; off >>= 1) {
        if (threadIdx.x < off) { redA[threadIdx.x] += redA[threadIdx.x + off]; redB[threadIdx.x] += redB[threadIdx.x + off]; }
        __syncthreads();
    }
    if (threadIdx.x == 0) {
        float su = redA[0], sq = redB[0];
        float var = (sq - su * su / 3072.0f) / 3071.0f;
        float* st = ws + (side ? OFF_STD_A : OFF_STD_E);
        st[gb * FF + f] = sqrtf(fmaxf(var, 0.0f));
    }
}

__global__ void k_derive(float* ws) {
    int k = blockIdx.x, gb = blockIdx.y;
    int f = k / 3, c = k % 3;
    for (int side = 0; side < 2; side++) {
        const float* P = ws + OFF_MAT + (size_t)side * MATSZ;
        float* V = ws + OFF_MAT + (size_t)(2 + side) * MATSZ;
        float* NP = ws + OFF_MAT + (size_t)(4 + side) * MATSZ;
        const float* mean = ws + (side ? OFF_MEAN_A : OFF_MEAN_E) + gb * 3;
        const float* st = ws + (side ? OFF_STD_A : OFF_STD_E) + gb * FF;
        float mm = mean[c];
        float rs = 1.0f / st[f];
        size_t base = ((size_t)gb * KF + k) * NG;
        for (int i = threadIdx.x; i < NG; i += 256) {
            float p = P[base + i];
            V[base + i] = f ? (p - P[base - 3 * NG + i]) : 0.0f;
            NP[base + i] = (p - mm) * rs;
        }
    }
}

__global__ void k_norms(float* ws) {
    int mat = blockIdx.x, gb = blockIdx.y;
    const float* M = ws + OFF_MAT + (size_t)mat * MATSZ + (size_t)gb * KF * NG;
    float* nr = ws + OFF_NORMS + ((size_t)mat * NGB + gb) * NG;
    for (int i = threadIdx.x; i < NG; i += 256) {
        float s = 0;
        for (int k = 0; k < KF; k++) { float v = M[(size_t)k * NG + i]; s += v * v; }
        nr[i] = s;
    }
}

// 128x128 fp32 tile, 8x8 per thread, d = sqrt(max(|a|^2+|b|^2-2ab, 1e-12))
__global__ __launch_bounds__(256) void k_gemm(float* ws, int cs) {
    int bx = blockIdx.x, by = blockIdx.y;
    int bz = blockIdx.z; int gbl = bz / 3, m = bz % 3;
    int gb = cs + gbl;
    int eIdx = (m == 0) ? 0 : ((m == 1) ? 4 : 2);
    int aIdx = (m == 0) ? 1 : ((m == 1) ? 5 : 3);
    const float* E = ws + OFF_MAT + (size_t)eIdx * MATSZ + (size_t)gb * KF * NG;
    const float* A = ws + OFF_MAT + (size_t)aIdx * MATSZ + (size_t)gb * KF * NG;
    const float* rnE = ws + OFF_NORMS + ((size_t)eIdx * NGB + gb) * NG;
    const float* cnA = ws + OFF_NORMS + ((size_t)aIdx * NGB + gb) * NG;
    float* D = ws + OFF_D + ((size_t)gbl * 3 + m) * (size_t)(NG * NG);
    int i0 = by * 128, j0 = bx * 128;
    __shared__ float4 Et[8][32], At[8][32];
    int tx = threadIdx.x, ty = threadIdx.y;
    int tid = ty * 16 + tx;
    float acc[2][2][4][4] = {};
    for (int k0 = 0; k0 < KF; k0 += 8) {
        {
            int kk = tid >> 5, i4 = tid & 31;
            Et[kk][i4] = *(const float4*)&E[(size_t)(k0 + kk) * NG + i0 + i4 * 4];
            At[kk][i4] = *(const float4*)&A[(size_t)(k0 + kk) * NG + j0 + i4 * 4];
        }
        __syncthreads();
#pragma unroll
        for (int kk = 0; kk < 8; kk++) {
            float4 e0 = Et[kk][ty], e1 = Et[kk][16 + ty];
            float4 a0 = At[kk][tx], a1 = At[kk][16 + tx];
            float er[2][4] = {{e0.x, e0.y, e0.z, e0.w}, {e1.x, e1.y, e1.z, e1.w}};
            float ar[2][4] = {{a0.x, a0.y, a0.z, a0.w}, {a1.x, a1.y, a1.z, a1.w}};
#pragma unroll
            for (int p = 0; p < 2; p++)
#pragma unroll
                for (int q = 0; q < 2; q++)
#pragma unroll
                    for (int r = 0; r < 4; r++)
#pragma unroll
                        for (int cc = 0; cc < 4; cc++)
                            acc[p][q][r][cc] += er[p][r] * ar[q][cc];
        }
        __syncthreads();
    }
    float rn[2][4], cn[2][4];
#pragma unroll
    for (int p = 0; p < 2; p++)
#pragma unroll
        for (int r = 0; r < 4; r++) rn[p][r] = rnE[i0 + p * 64 + ty * 4 + r];
#pragma unroll
    for (int q = 0; q < 2; q++)
#pragma unroll
        for (int cc = 0; cc < 4; cc++) cn[q][cc] = cnA[j0 + q * 64 + tx * 4 + cc];
#pragma unroll
    for (int p = 0; p < 2; p++)
#pragma unroll
        for (int r = 0; r < 4; r++) {
            int gi = i0 + p * 64 + ty * 4 + r;
#pragma unroll
            for (int q = 0; q < 2; q++) {
                float4 o;
                float d0 = rn[p][r] + cn[q][0] - 2.0f * acc[p][q][r][0];
                float d1 = rn[p][r] + cn[q][1] - 2.0f * acc[p][q][r][1];
                float d2_ = rn[p][r] + cn[q][2] - 2.0f * acc[p][q][r][2];
                float d3 = rn[p][r] + cn[q][3] - 2.0f * acc[p][q][r][3];
                o.x = sqrtf(fmaxf(d0, 1e-12f));
                o.y = sqrtf(fmaxf(d1, 1e-12f));
                o.z = sqrtf(fmaxf(d2_, 1e-12f));
                o.w = sqrtf(fmaxf(d3, 1e-12f));
                *(float4*)&D[(size_t)gi * NG + j0 + q * 64 + tx * 4] = o;
            }
        }
}

// per-row top-16 selection: wave per row, values held in registers
__global__ void k_select(float* ws, int cs) {
    int gbl = blockIdx.y; int gb = cs + gbl;
    int w = threadIdx.x >> 6, lane = threadIdx.x & 63;
    int row = blockIdx.x * 4 + w;
    const float* Dbase = ws + OFF_D + (size_t)gbl * 3 * (size_t)(NG * NG);
    const float* dg = Dbase + (size_t)row * NG;
    const float* dn = Dbase + (size_t)(NG * NG) + (size_t)row * NG;
    const float* dv = Dbase + (size_t)2 * (NG * NG) + (size_t)row * NG;
    float dgv[16], dnv[16], dvv[16];
#pragma unroll
    for (int q = 0; q < 16; q++) {
        dgv[q] = dg[q * 64 + lane];
        dnv[q] = dn[q * 64 + lane];
        dvv[q] = dv[q * 64 + lane];
    }
    float sg = 0, sv = 0, sn = 0;
    for (int it = 0; it < KNN; it++) {
        float best = 3.4e38f; int bc = 1 << 30;
#pragma unroll
        for (int q = 0; q < 16; q++) { float v = dgv[q]; int c = q * 64 + lane; if (v < best) { best = v; bc = c; } }
#pragma unroll
        for (int off = 32; off; off >>= 1) {
            float ov = __shfl_xor(best, off); int oc = __shfl_xor(bc, off);
            if (ov < best || (ov == best && oc < bc)) { best = ov; bc = oc; }
        }
        sg += best;
        int bq = bc >> 6, bl = bc & 63;
        float t = 0;
#pragma unroll
        for (int q = 0; q < 16; q++) if (q == bq) t = dvv[q];
        t = __shfl(t, bl); sv += t;
        if (lane == bl) {
#pragma unroll
            for (int q = 0; q < 16; q++) if (q == bq) dgv[q] = 3.4e38f;
        }
    }
    for (int it = 0; it < KNN; it++) {
        float best = 3.4e38f; int bc = 1 << 30;
#pragma unroll
        for (int q = 0; q < 16; q++) { float v = dnv[q]; int c = q * 64 + lane; if (v < best) { best = v; bc = c; } }
#pragma unroll
        for (int off = 32; off; off >>= 1) {
            float ov = __shfl_xor(best, off); int oc = __shfl_xor(bc, off);
            if (ov < best || (ov == best && oc < bc)) { best = ov; bc = oc; }
        }
        sn += best;
        int bq = bc >> 6, bl = bc & 63;
        if (lane == bl) {
#pragma unroll
            for (int q = 0; q < 16; q++) if (q == bq) dnv[q] = 3.4e38f;
        }
    }
    __shared__ float ssum[4][3];
    if (lane == 0) { ssum[w][0] = sg; ssum[w][1] = sn; ssum[w][2] = sv; }
    __syncthreads();
    if (threadIdx.x == 0) {
        float* part = ws + OFF_PART + ((size_t)gb * 256 + blockIdx.x) * 3;
        part[0] = ssum[0][0] + ssum[1][0] + ssum[2][0] + ssum[3][0];
        part[1] = ssum[0][1] + ssum[1][1] + ssum[2][1] + ssum[3][1];
        part[2] = ssum[0][2] + ssum[1][2] + ssum[2][2] + ssum[3][2];
    }
}

__global__ void k_reduce(float* ws, float* out) {
    double s[3] = {0, 0, 0};
    for (int idx = threadIdx.x; idx < 8192; idx += 256) {
        const float* p = ws + OFF_PART + (size_t)idx * 3;
        s[0] += p[0]; s[1] += p[1]; s[2] += p[2];
    }
    __shared__ double red[256];
    for (int m = 0; m < 3; m++) {
        red[threadIdx.x] = s[m]; __syncthreads();
        for (int off = 128; off; off >>= 1) { if (threadIdx.x < off) red[threadIdx.x] += red[threadIdx.x + off]; __syncthreads(); }
        if (threadIdx.x == 0) out[m] = (float)(red[0] / 524288.0 / 8.0);
        __syncthreads();
    }
}

extern "C" void kernel_launch(void* const* d_in, const int* in_sizes, int n_in,
                              void* d_out, int out_size, void* d_ws, size_t ws_size,
                              hipStream_t stream) {
    const float* ex = (const float*)d_in[0];
    const float* ac = (const float*)d_in[1];
    float* ws = (float*)d_ws;
    float* out = (float*)d_out;

    hipLaunchKernelGGL(k_bg, dim3(32), dim3(256), 0, stream, ex, ac, ws);
    hipLaunchKernelGGL(k_order, dim3(1), dim3(1024), 0, stream, ws);
    hipLaunchKernelGGL(k_gather, dim3(FF, NGB), dim3(256), 0, stream, ex, ac, ws);
    hipLaunchKernelGGL(k_mean, dim3(NGB, 2), dim3(256), 0, stream, ws);
    hipLaunchKernelGGL(k_std, dim3(NGB, FF, 2), dim3(128), 0, stream, ws);
    hipLaunchKernelGGL(k_derive, dim3(KF, NGB), dim3(256), 0, stream, ws);
    hipLaunchKernelGGL(k_norms, dim3(6, NGB), dim3(256), 0, stream, ws);

    size_t ws_floats = ws_size / 4;
    size_t dcap = (ws_floats > (size_t)OFF_D) ? (ws_floats - (size_t)OFF_D) : 0;
    int gbc = (int)(dcap / (3ull * NG * NG));
    if (gbc < 1) gbc = 1;
    if (gbc > 32) gbc = 32;
    for (int cs = 0; cs < NGB; cs += gbc) {
        int take = (NGB - cs < gbc) ? (NGB - cs) : gbc;
        hipLaunchKernelGGL(k_gemm, dim3(8, 8, take * 3), dim3(16, 16), 0, stream, ws, cs);
        hipLaunchKernelGGL(k_select, dim3(256, take), dim3(256), 0, stream, ws, cs);
    }
    hipLaunchKernelGGL(k_reduce, dim3(1), dim3(256), 0, stream, ws, out);
}

// Round 2
// 985.133 us; speedup vs baseline: 1.2406x; 1.2406x over previous
//
#include <hip/hip_runtime.h>
#include <math.h>

#define GGRP 8
#define NPTS 8192
#define NG   1024      // points per group
#define BB   4
#define FF   64
#define CH   11
#define KF   192       // feature dim F*3
#define NGB  32        // G*B
#define KNN  16

// ws offsets in FLOATS
#define OFF_ORD_E  0        // 8192 int
#define OFF_ORD_A  8192     // 8192 int
#define OFF_BG_E   16384    // 8192 int
#define OFF_BG_A   24576    // 8192 int
#define OFF_MEAN_E 33024    // 96 f
#define OFF_MEAN_A 33152    // 96 f
#define OFF_STD_E  33280    // 2048 f
#define OFF_STD_A  35328    // 2048 f
#define OFF_PART   40960    // 8192*3 f
#define OFF_NORMS  65536    // 6*32*1024 f
#define OFF_MAT    262144
#define MATSZ      6291456  // 32*192*1024 floats per matrix-set
#define OFF_D      38010880 // OFF_MAT + 6*MATSZ (fallback-path D)
// bf16 region overlays after fp32 mats (fast path)
#define OFF_BMAT   38010880                  // ushort* base (floats offset)
#define BMAT_FLOATS 18874368                 // 6*32*1024*192 ushorts / 2
#define OFF_D2     56885248                  // OFF_BMAT + BMAT_FLOATS
// matrix order: 0 PE, 1 PA, 2 VE, 3 VA, 4 NPE, 5 NPA

typedef short bf16x8 __attribute__((ext_vector_type(8)));
typedef float f32x4 __attribute__((ext_vector_type(4)));

__global__ void k_bg(const float* __restrict__ ex, const float* __restrict__ ac, float* ws) {
    int n = blockIdx.x * blockDim.x + threadIdx.x;
    if (n >= NPTS) return;
    int* bg_e = (int*)ws + OFF_BG_E;
    int* bg_a = (int*)ws + OFF_BG_A;
    const float* pe = ex + (size_t)n * CH + 3;
    const float* pa = ac + (size_t)n * CH + 3;
    float m = -1e30f; int a = 0;
    for (int c = 0; c < GGRP; c++) { float v = pe[c]; if (v > m) { m = v; a = c; } }
    bg_e[n] = a;
    m = -1e30f; a = 0;
    for (int c = 0; c < GGRP; c++) { float v = pa[c]; if (v > m) { m = v; a = c; } }
    bg_a[n] = a;
}

// stable counting-compaction: 16 waves, wave w<8 -> expected group w, w>=8 -> actual group w-8
__global__ void k_order(float* ws) {
    int tid = threadIdx.x;
    int w = tid >> 6, lane = tid & 63;
    const int* bg = (const int*)ws + ((w < 8) ? OFF_BG_E : OFF_BG_A);
    int* ord = (int*)ws + ((w < 8) ? OFF_ORD_E : OFF_ORD_A);
    int grp = w & 7;
    __shared__ int cnts[16];
    int cnt = 0;
    for (int base = 0; base < NPTS; base += 64) {
        int v = bg[base + lane];
        unsigned long long m = __ballot(v == grp);
        cnt += __popcll(m);
    }
    if (lane == 0) cnts[w] = cnt;
    __syncthreads();
    int pos = 0;
    for (int g2 = 0; g2 < grp; g2++) pos += cnts[(w & 8) | g2];
    for (int base = 0; base < NPTS; base += 64) {
        int v = bg[base + lane];
        unsigned long long m = __ballot(v == grp);
        int pre = __popcll(m & ((1ull << lane) - 1ull));
        if (v == grp) { int slot = pos + pre; if (slot < NPTS) ord[slot] = base + lane; }
        pos += __popcll(m);
    }
}

// build PE_T / PA_T : layout [gb][k=f*3+c][i]
__global__ void k_gather(const float* __restrict__ ex, const float* __restrict__ ac, float* ws) {
    int f = blockIdx.x, gb = blockIdx.y;
    int g = gb >> 2, b = gb & 3;
    const int* ord_e = (const int*)ws + OFF_ORD_E;
    const int* ord_a = (const int*)ws + OFF_ORD_A;
    float* PE = ws + OFF_MAT;
    float* PA = ws + OFF_MAT + (size_t)1 * MATSZ;
    size_t mbase = ((size_t)gb * KF + f * 3) * NG;
    size_t sbase = ((size_t)(b * FF + f)) * NPTS;
    for (int i = threadIdx.x; i < NG; i += blockDim.x) {
        int ne = ord_e[g * NG + i];
        const float* p = ex + (sbase + ne) * CH;
        PE[mbase + i] = p[0]; PE[mbase + NG + i] = p[1]; PE[mbase + 2 * NG + i] = p[2];
        int na = ord_a[g * NG + i];
        const float* q = ac + (sbase + na) * CH;
        PA[mbase + i] = q[0]; PA[mbase + NG + i] = q[1]; PA[mbase + 2 * NG + i] = q[2];
    }
}

__global__ void k_mean(float* ws) {
    int gb = blockIdx.x, side = blockIdx.y;
    const float* M = ws + OFF_MAT + (size_t)side * MATSZ + (size_t)gb * KF * NG;
    float* mean = ws + (side ? OFF_MEAN_A : OFF_MEAN_E) + gb * 3;
    float s0 = 0, s1 = 0, s2 = 0;
    for (int idx = threadIdx.x; idx < KF * NG; idx += 256) {
        int k = idx >> 10; int c = k % 3;
        float v = M[idx];
        if (c == 0) s0 += v; else if (c == 1) s1 += v; else s2 += v;
    }
    __shared__ float red[256];
    for (int c = 0; c < 3; c++) {
        float s = (c == 0) ? s0 : ((c == 1) ? s1 : s2);
        red[threadIdx.x] = s; __syncthreads();
        for (int off = 128; off; off >>= 1) { if (threadIdx.x < off) red[threadIdx.x] += red[threadIdx.x + off]; __syncthreads(); }
        if (threadIdx.x == 0) mean[c] = red[0] / (float)(FF * NG);
        __syncthreads();
    }
}

// std over (n,3) of centered data, ddof=1, WITH its own mean subtraction (two-sum form)
__global__ void k_std(float* ws) {
    int gb = blockIdx.x, f = blockIdx.y, side = blockIdx.z;
    const float* M = ws + OFF_MAT + (size_t)side * MATSZ + ((size_t)gb * KF + f * 3) * NG;
    const float* mean = ws + (side ? OFF_MEAN_A : OFF_MEAN_E) + gb * 3;
    float m0 = mean[0], m1 = mean[1], m2 = mean[2];
    float s2 = 0, s1 = 0;
    for (int idx = threadIdx.x; idx < 3 * NG; idx += 128) {
        int c = idx >> 10;
        float mm = (c == 0) ? m0 : ((c == 1) ? m1 : m2);
        float v = M[idx] - mm;
        s1 += v; s2 += v * v;
    }
    __shared__ float redA[128], redB[128];
    redA[threadIdx.x] = s1; redB[threadIdx.x] = s2; __syncthreads();
    for (int off = 64; off; off >>= 1) {
        if (threadIdx.x < off) { redA[threadIdx.x] += redA[threadIdx.x + off]; redB[threadIdx.x] += redB[threadIdx.x + off]; }
        __syncthreads();
    }
    if (threadIdx.x == 0) {
        float su = redA[0], sq = redB[0];
        float var = (sq - su * su / 3072.0f) / 3071.0f;
        float* st = ws + (side ? OFF_STD_A : OFF_STD_E);
        st[gb * FF + f] = sqrtf(fmaxf(var, 0.0f));
    }
}

__global__ void k_derive(float* ws) {
    int k = blockIdx.x, gb = blockIdx.y;
    int f = k / 3, c = k % 3;
    for (int side = 0; side < 2; side++) {
        const float* P = ws + OFF_MAT + (size_t)side * MATSZ;
        float* V = ws + OFF_MAT + (size_t)(2 + side) * MATSZ;
        float* NP = ws + OFF_MAT + (size_t)(4 + side) * MATSZ;
        const float* mean = ws + (side ? OFF_MEAN_A : OFF_MEAN_E) + gb * 3;
        const float* st = ws + (side ? OFF_STD_A : OFF_STD_E) + gb * FF;
        float mm = mean[c];
        float rs = 1.0f / st[f];
        size_t base = ((size_t)gb * KF + k) * NG;
        for (int i = threadIdx.x; i < NG; i += 256) {
            float p = P[base + i];
            V[base + i] = f ? (p - P[base - 3 * NG + i]) : 0.0f;
            NP[base + i] = (p - mm) * rs;
        }
    }
}

__global__ void k_norms(float* ws) {
    int mat = blockIdx.x, gb = blockIdx.y;
    const float* M = ws + OFF_MAT + (size_t)mat * MATSZ + (size_t)gb * KF * NG;
    float* nr = ws + OFF_NORMS + ((size_t)mat * NGB + gb) * NG;
    for (int i = threadIdx.x; i < NG; i += 256) {
        float s = 0;
        for (int k = 0; k < KF; k++) { float v = M[(size_t)k * NG + i]; s += v * v; }
        nr[i] = s;
    }
}

// transpose-convert fp32 [k][i] -> bf16 row-major [i][k]
__global__ void k_tobf16(float* ws) {
    int x = blockIdx.x;            // 0..47: it = x&15, kt = x>>4
    int it = x & 15, kt = x >> 4;
    int gb = blockIdx.y, mat = blockIdx.z;
    const float* M = ws + OFF_MAT + (size_t)mat * MATSZ + (size_t)gb * KF * NG;
    unsigned short* out = (unsigned short*)(ws + OFF_BMAT) + ((size_t)mat * NGB + gb) * (size_t)(NG * KF);
    __shared__ float tile[64][65];
    int i0 = it * 64, k0 = kt * 64;
    int t = threadIdx.x;
    int ii = t & 63, kq = t >> 6;
#pragma unroll
    for (int rep = 0; rep < 16; rep++) {
        int kk = kq + rep * 4;
        tile[kk][ii] = M[(size_t)(k0 + kk) * NG + i0 + ii];
    }
    __syncthreads();
    int kk2 = t & 63, iq = t >> 6;
#pragma unroll
    for (int rep = 0; rep < 16; rep++) {
        int i2 = iq + rep * 4;
        float v = tile[kk2][i2];
        unsigned u = __builtin_bit_cast(unsigned, v);
        unsigned r = (u + 0x7fffu + ((u >> 16) & 1u)) >> 16;   // RNE bf16
        out[(size_t)(i0 + i2) * KF + k0 + kk2] = (unsigned short)r;
    }
}

// MFMA distance GEMM: 128x128 tile, 4 waves (2x2), BK=64, swizzled LDS
__global__ __launch_bounds__(256) void k_mgemm(float* ws, int cs, unsigned long long dOff) {
    int bx = blockIdx.x, by = blockIdx.y;
    int bz = blockIdx.z; int gbl = bz / 3, m3 = bz % 3;
    int gb = cs + gbl;
    int eIdx = (m3 == 0) ? 0 : ((m3 == 1) ? 4 : 2);
    int aIdx = (m3 == 0) ? 1 : ((m3 == 1) ? 5 : 3);
    const unsigned short* bmat = (const unsigned short*)(ws + OFF_BMAT);
    const unsigned short* Eg = bmat + ((size_t)eIdx * NGB + gb) * (size_t)(NG * KF);
    const unsigned short* Ag = bmat + ((size_t)aIdx * NGB + gb) * (size_t)(NG * KF);
    const float* rnE = ws + OFF_NORMS + ((size_t)eIdx * NGB + gb) * NG;
    const float* cnA = ws + OFF_NORMS + ((size_t)aIdx * NGB + gb) * NG;
    float* D = ws + dOff + ((size_t)gbl * 3 + m3) * (size_t)(NG * NG);
    int i0 = by * 128, j0 = bx * 128;
    __shared__ unsigned short lE[128 * 64];
    __shared__ unsigned short lA[128 * 64];
    int tid = threadIdx.x;
    int wid = tid >> 6, lane = tid & 63;
    int wr = wid >> 1, wc = wid & 1;
    f32x4 acc[4][4];
#pragma unroll
    for (int m = 0; m < 4; m++)
#pragma unroll
        for (int n = 0; n < 4; n++) acc[m][n] = (f32x4){0.f, 0.f, 0.f, 0.f};

    int rr = lane >> 3, ss = lane & 7;
    for (int k0 = 0; k0 < KF; k0 += 64) {
        if (k0) __syncthreads();
#pragma unroll
        for (int q = 0; q < 4; q++) {
            int r0 = wid * 32 + q * 8;
            int r = r0 + rr;
            int c = ss ^ (r & 7);
            __builtin_amdgcn_global_load_lds(
                (const __attribute__((address_space(1))) void*)(Eg + (size_t)(i0 + r) * KF + k0 + c * 8),
                (__attribute__((address_space(3))) void*)&lE[r0 * 64], 16, 0, 0);
            __builtin_amdgcn_global_load_lds(
                (const __attribute__((address_space(1))) void*)(Ag + (size_t)(j0 + r) * KF + k0 + c * 8),
                (__attribute__((address_space(3))) void*)&lA[r0 * 64], 16, 0, 0);
        }
        asm volatile("s_waitcnt vmcnt(0)" ::: "memory");
        __syncthreads();
#pragma unroll
        for (int ks = 0; ks < 2; ks++) {
            bf16x8 af[4], bfr[4];
            int kb = ks * 64 + (lane >> 4) * 16;
#pragma unroll
            for (int m = 0; m < 4; m++) {
                int arow = wr * 64 + m * 16 + (lane & 15);
                af[m] = *(const bf16x8*)((const char*)lE + arow * 128 + (kb ^ ((arow & 7) << 4)));
            }
#pragma unroll
            for (int n = 0; n < 4; n++) {
                int brow = wc * 64 + n * 16 + (lane & 15);
                bfr[n] = *(const bf16x8*)((const char*)lA + brow * 128 + (kb ^ ((brow & 7) << 4)));
            }
#pragma unroll
            for (int m = 0; m < 4; m++)
#pragma unroll
                for (int n = 0; n < 4; n++)
                    acc[m][n] = __builtin_amdgcn_mfma_f32_16x16x32_bf16(af[m], bfr[n], acc[m][n], 0, 0, 0);
        }
    }

    int colbase = j0 + wc * 64 + (lane & 15);
    int rowbase = i0 + wr * 64 + ((lane >> 4) << 2);
    float cn[4];
#pragma unroll
    for (int n = 0; n < 4; n++) cn[n] = cnA[colbase + n * 16];
#pragma unroll
    for (int m = 0; m < 4; m++) {
        int rb = rowbase + m * 16;
#pragma unroll
        for (int r = 0; r < 4; r++) {
            float rn = rnE[rb + r];
#pragma unroll
            for (int n = 0; n < 4; n++) {
                float d = rn + cn[n] - 2.0f * acc[m][n][r];
                D[(size_t)(rb + r) * NG + colbase + n * 16] = sqrtf(fmaxf(d, 1e-12f));
            }
        }
    }
}

// fallback fp32 GEMM (small-ws path), unchanged
__global__ __launch_bounds__(256) void k_gemm(float* ws, int cs) {
    int bx = blockIdx.x, by = blockIdx.y;
    int bz = blockIdx.z; int gbl = bz / 3, m = bz % 3;
    int gb = cs + gbl;
    int eIdx = (m == 0) ? 0 : ((m == 1) ? 4 : 2);
    int aIdx = (m == 0) ? 1 : ((m == 1) ? 5 : 3);
    const float* E = ws + OFF_MAT + (size_t)eIdx * MATSZ + (size_t)gb * KF * NG;
    const float* A = ws + OFF_MAT + (size_t)aIdx * MATSZ + (size_t)gb * KF * NG;
    const float* rnE = ws + OFF_NORMS + ((size_t)eIdx * NGB + gb) * NG;
    const float* cnA = ws + OFF_NORMS + ((size_t)aIdx * NGB + gb) * NG;
    float* D = ws + OFF_D + ((size_t)gbl * 3 + m) * (size_t)(NG * NG);
    int i0 = by * 128, j0 = bx * 128;
    __shared__ float4 Et[8][32], At[8][32];
    int tx = threadIdx.x, ty = threadIdx.y;
    int tid = ty * 16 + tx;
    float acc[2][2][4][4] = {};
    for (int k0 = 0; k0 < KF; k0 += 8) {
        {
            int kk = tid >> 5, i4 = tid & 31;
            Et[kk][i4] = *(const float4*)&E[(size_t)(k0 + kk) * NG + i0 + i4 * 4];
            At[kk][i4] = *(const float4*)&A[(size_t)(k0 + kk) * NG + j0 + i4 * 4];
        }
        __syncthreads();
#pragma unroll
        for (int kk = 0; kk < 8; kk++) {
            float4 e0 = Et[kk][ty], e1 = Et[kk][16 + ty];
            float4 a0 = At[kk][tx], a1 = At[kk][16 + tx];
            float er[2][4] = {{e0.x, e0.y, e0.z, e0.w}, {e1.x, e1.y, e1.z, e1.w}};
            float ar[2][4] = {{a0.x, a0.y, a0.z, a0.w}, {a1.x, a1.y, a1.z, a1.w}};
#pragma unroll
            for (int p = 0; p < 2; p++)
#pragma unroll
                for (int q = 0; q < 2; q++)
#pragma unroll
                    for (int r = 0; r < 4; r++)
#pragma unroll
                        for (int cc = 0; cc < 4; cc++)
                            acc[p][q][r][cc] += er[p][r] * ar[q][cc];
        }
        __syncthreads();
    }
    float rn[2][4], cn[2][4];
#pragma unroll
    for (int p = 0; p < 2; p++)
#pragma unroll
        for (int r = 0; r < 4; r++) rn[p][r] = rnE[i0 + p * 64 + ty * 4 + r];
#pragma unroll
    for (int q = 0; q < 2; q++)
#pragma unroll
        for (int cc = 0; cc < 4; cc++) cn[q][cc] = cnA[j0 + q * 64 + tx * 4 + cc];
#pragma unroll
    for (int p = 0; p < 2; p++)
#pragma unroll
        for (int r = 0; r < 4; r++) {
            int gi = i0 + p * 64 + ty * 4 + r;
#pragma unroll
            for (int q = 0; q < 2; q++) {
                float4 o;
                float d0 = rn[p][r] + cn[q][0] - 2.0f * acc[p][q][r][0];
                float d1 = rn[p][r] + cn[q][1] - 2.0f * acc[p][q][r][1];
                float d2_ = rn[p][r] + cn[q][2] - 2.0f * acc[p][q][r][2];
                float d3 = rn[p][r] + cn[q][3] - 2.0f * acc[p][q][r][3];
                o.x = sqrtf(fmaxf(d0, 1e-12f));
                o.y = sqrtf(fmaxf(d1, 1e-12f));
                o.z = sqrtf(fmaxf(d2_, 1e-12f));
                o.w = sqrtf(fmaxf(d3, 1e-12f));
                *(float4*)&D[(size_t)gi * NG + j0 + q * 64 + tx * 4] = o;
            }
        }
}

// per-row top-16 selection: wave per row, values held in registers
__global__ void k_select(float* ws, int cs, unsigned long long dOff) {
    int gbl = blockIdx.y; int gb = cs + gbl;
    int w = threadIdx.x >> 6, lane = threadIdx.x & 63;
    int row = blockIdx.x * 4 + w;
    const float* Dbase = ws + dOff + (size_t)gbl * 3 * (size_t)(NG * NG);
    const float* dg = Dbase + (size_t)row * NG;
    const float* dn = Dbase + (size_t)(NG * NG) + (size_t)row * NG;
    const float* dv = Dbase + (size_t)2 * (NG * NG) + (size_t)row * NG;
    float dgv[16], dnv[16], dvv[16];
#pragma unroll
    for (int q = 0; q < 16; q++) {
        dgv[q] = dg[q * 64 + lane];
        dnv[q] = dn[q * 64 + lane];
        dvv[q] = dv[q * 64 + lane];
    }
    float sg = 0, sv = 0, sn = 0;
    for (int it = 0; it < KNN; it++) {
        float best = 3.4e38f; int bc = 1 << 30;
#pragma unroll
        for (int q = 0; q < 16; q++) { float v = dgv[q]; int c = q * 64 + lane; if (v < best) { best = v; bc = c; } }
#pragma unroll
        for (int off = 32; off; off >>= 1) {
            float ov = __shfl_xor(best, off); int oc = __shfl_xor(bc, off);
            if (ov < best || (ov == best && oc < bc)) { best = ov; bc = oc; }
        }
        sg += best;
        int bq = bc >> 6, bl = bc & 63;
        float t = 0;
#pragma unroll
        for (int q = 0; q < 16; q++) if (q == bq) t = dvv[q];
        t = __shfl(t, bl); sv += t;
        if (lane == bl) {
#pragma unroll
            for (int q = 0; q < 16; q++) if (q == bq) dgv[q] = 3.4e38f;
        }
    }
    for (int it = 0; it < KNN; it++) {
        float best = 3.4e38f; int bc = 1 << 30;
#pragma unroll
        for (int q = 0; q < 16; q++) { float v = dnv[q]; int c = q * 64 + lane; if (v < best) { best = v; bc = c; } }
#pragma unroll
        for (int off = 32; off; off >>= 1) {
            float ov = __shfl_xor(best, off); int oc = __shfl_xor(bc, off);
            if (ov < best || (ov == best && oc < bc)) { best = ov; bc = oc; }
        }
        sn += best;
        int bq = bc >> 6, bl = bc & 63;
        if (lane == bl) {
#pragma unroll
            for (int q = 0; q < 16; q++) if (q == bq) dnv[q] = 3.4e38f;
        }
    }
    __shared__ float ssum[4][3];
    if (lane == 0) { ssum[w][0] = sg; ssum[w][1] = sn; ssum[w][2] = sv; }
    __syncthreads();
    if (threadIdx.x == 0) {
        float* part = ws + OFF_PART + ((size_t)gb * 256 + blockIdx.x) * 3;
        part[0] = ssum[0][0] + ssum[1][0] + ssum[2][0] + ssum[3][0];
        part[1] = ssum[0][1] + ssum[1][1] + ssum[2][1] + ssum[3][1];
        part[2] = ssum[0][2] + ssum[1][2] + ssum[2][2] + ssum[3][2];
    }
}

__global__ void k_reduce(float* ws, float* out) {
    double s[3] = {0, 0, 0};
    for (int idx = threadIdx.x; idx < 8192; idx += 256) {
        const float* p = ws + OFF_PART + (size_t)idx * 3;
        s[0] += p[0]; s[1] += p[1]; s[2] += p[2];
    }
    __shared__ double red[256];
    for (int m = 0; m < 3; m++) {
        red[threadIdx.x] = s[m]; __syncthreads();
        for (int off = 128; off; off >>= 1) { if (threadIdx.x < off) red[threadIdx.x] += red[threadIdx.x + off]; __syncthreads(); }
        if (threadIdx.x == 0) out[m] = (float)(red[0] / 524288.0 / 8.0);
        __syncthreads();
    }
}

extern "C" void kernel_launch(void* const* d_in, const int* in_sizes, int n_in,
                              void* d_out, int out_size, void* d_ws, size_t ws_size,
                              hipStream_t stream) {
    const float* ex = (const float*)d_in[0];
    const float* ac = (const float*)d_in[1];
    float* ws = (float*)d_ws;
    float* out = (float*)d_out;

    hipLaunchKernelGGL(k_bg, dim3(32), dim3(256), 0, stream, ex, ac, ws);
    hipLaunchKernelGGL(k_order, dim3(1), dim3(1024), 0, stream, ws);
    hipLaunchKernelGGL(k_gather, dim3(FF, NGB), dim3(256), 0, stream, ex, ac, ws);
    hipLaunchKernelGGL(k_mean, dim3(NGB, 2), dim3(256), 0, stream, ws);
    hipLaunchKernelGGL(k_std, dim3(NGB, FF, 2), dim3(128), 0, stream, ws);
    hipLaunchKernelGGL(k_derive, dim3(KF, NGB), dim3(256), 0, stream, ws);
    hipLaunchKernelGGL(k_norms, dim3(6, NGB), dim3(256), 0, stream, ws);

    size_t ws_floats = ws_size / 4;
    bool fast = ws_floats >= (size_t)OFF_D2 + 3ull * NG * NG;

    if (fast) {
        hipLaunchKernelGGL(k_tobf16, dim3(48, NGB, 6), dim3(256), 0, stream, ws);
        size_t dcap = ws_floats - (size_t)OFF_D2;
        int gbc = (int)(dcap / (3ull * NG * NG));
        if (gbc > 32) gbc = 32;
        for (int cs = 0; cs < NGB; cs += gbc) {
            int take = (NGB - cs < gbc) ? (NGB - cs) : gbc;
            hipLaunchKernelGGL(k_mgemm, dim3(8, 8, take * 3), dim3(256), 0, stream, ws, cs, (unsigned long long)OFF_D2);
            hipLaunchKernelGGL(k_select, dim3(256, take), dim3(256), 0, stream, ws, cs, (unsigned long long)OFF_D2);
        }
    } else {
        size_t dcap = (ws_floats > (size_t)OFF_D) ? (ws_floats - (size_t)OFF_D) : 0;
        int gbc = (int)(dcap / (3ull * NG * NG));
        if (gbc < 1) gbc = 1;
        if (gbc > 32) gbc = 32;
        for (int cs = 0; cs < NGB; cs += gbc) {
            int take = (NGB - cs < gbc) ? (NGB - cs) : gbc;
            hipLaunchKernelGGL(k_gemm, dim3(8, 8, take * 3), dim3(16, 16), 0, stream, ws, cs);
            hipLaunchKernelGGL(k_select, dim3(256, take), dim3(256), 0, stream, ws, cs, (unsigned long long)OFF_D);
        }
    }
    hipLaunchKernelGGL(k_reduce, dim3(1), dim3(256), 0, stream, ws, out);
}

// Round 3
// 632.735 us; speedup vs baseline: 1.9315x; 1.5569x over previous
//
#include <hip/hip_runtime.h>
#include <math.h>

#define GGRP 8
#define NPTS 8192
#define NG   1024      // points per group
#define BB   4
#define FF   64
#define CH   11
#define KF   192       // feature dim F*3
#define NGB  32        // G*B
#define KNN  16

// ws offsets in FLOATS
#define OFF_ORD_E  0        // 8192 int
#define OFF_ORD_A  8192     // 8192 int
#define OFF_BG_E   16384    // 8192 int
#define OFF_BG_A   24576    // 8192 int
#define OFF_MEAN_E 32768    // 96 f
#define OFF_MEAN_A 32896    // 96 f
#define OFF_STD_E  33024    // 2048 f
#define OFF_STD_A  35072    // 2048 f
#define OFF_MEANP  37888    // 2*32*64*3 = 12288 f
#define OFF_PART   50176    // 8192*3 f
#define OFF_NORMP  74752    // 6*32*3*1024 = 589824 f
#define OFF_NORMS  664576   // 6*32*1024 = 196608 f
#define OFF_MAT    1048576
#define MATSZ      6291456  // 32*192*1024 floats per matrix-set
#define OFF_BMAT   38797312 // OFF_MAT + 6*MATSZ ; bf16 mats (fast) / D (fallback)
#define BMAT_FLOATS 18874368
#define FAST_END   57671680 // OFF_BMAT + BMAT_FLOATS
#define OFF_D      38797312 // fallback D region
// matrix order: 0 PE, 1 PA, 2 VE, 3 VA, 4 NPE, 5 NPA

typedef short bf16x8 __attribute__((ext_vector_type(8)));
typedef float f32x4 __attribute__((ext_vector_type(4)));

__global__ void k_bg(const float* __restrict__ ex, const float* __restrict__ ac, float* ws) {
    int n = blockIdx.x * blockDim.x + threadIdx.x;
    if (n >= NPTS) return;
    int* bg_e = (int*)ws + OFF_BG_E;
    int* bg_a = (int*)ws + OFF_BG_A;
    const float* pe = ex + (size_t)n * CH + 3;
    const float* pa = ac + (size_t)n * CH + 3;
    float m = -1e30f; int a = 0;
    for (int c = 0; c < GGRP; c++) { float v = pe[c]; if (v > m) { m = v; a = c; } }
    bg_e[n] = a;
    m = -1e30f; a = 0;
    for (int c = 0; c < GGRP; c++) { float v = pa[c]; if (v > m) { m = v; a = c; } }
    bg_a[n] = a;
}

// stable counting-compaction: 16 waves, wave w<8 -> expected group w, w>=8 -> actual group w-8
__global__ void k_order(float* ws) {
    int tid = threadIdx.x;
    int w = tid >> 6, lane = tid & 63;
    const int* bg = (const int*)ws + ((w < 8) ? OFF_BG_E : OFF_BG_A);
    int* ord = (int*)ws + ((w < 8) ? OFF_ORD_E : OFF_ORD_A);
    int grp = w & 7;
    __shared__ int cnts[16];
    int cnt = 0;
    for (int base = 0; base < NPTS; base += 64) {
        int v = bg[base + lane];
        unsigned long long m = __ballot(v == grp);
        cnt += __popcll(m);
    }
    if (lane == 0) cnts[w] = cnt;
    __syncthreads();
    int pos = 0;
    for (int g2 = 0; g2 < grp; g2++) pos += cnts[(w & 8) | g2];
    for (int base = 0; base < NPTS; base += 64) {
        int v = bg[base + lane];
        unsigned long long m = __ballot(v == grp);
        int pre = __popcll(m & ((1ull << lane) - 1ull));
        if (v == grp) { int slot = pos + pre; if (slot < NPTS) ord[slot] = base + lane; }
        pos += __popcll(m);
    }
}

// build PE_T / PA_T : layout [gb][k=f*3+c][i] ; also per-(gb,f) coord-sum partials
__global__ void k_gather(const float* __restrict__ ex, const float* __restrict__ ac, float* ws) {
    int f = blockIdx.x, gb = blockIdx.y;
    int g = gb >> 2, b = gb & 3;
    const int* ord_e = (const int*)ws + OFF_ORD_E;
    const int* ord_a = (const int*)ws + OFF_ORD_A;
    float* PE = ws + OFF_MAT;
    float* PA = ws + OFF_MAT + (size_t)1 * MATSZ;
    size_t mbase = ((size_t)gb * KF + f * 3) * NG;
    size_t sbase = ((size_t)(b * FF + f)) * NPTS;
    float sums[6] = {0, 0, 0, 0, 0, 0};
    for (int i = threadIdx.x; i < NG; i += blockDim.x) {
        int ne = ord_e[g * NG + i];
        const float* p = ex + (sbase + ne) * CH;
        float e0 = p[0], e1 = p[1], e2 = p[2];
        PE[mbase + i] = e0; PE[mbase + NG + i] = e1; PE[mbase + 2 * NG + i] = e2;
        sums[0] += e0; sums[1] += e1; sums[2] += e2;
        int na = ord_a[g * NG + i];
        const float* q = ac + (sbase + na) * CH;
        float a0 = q[0], a1 = q[1], a2 = q[2];
        PA[mbase + i] = a0; PA[mbase + NG + i] = a1; PA[mbase + 2 * NG + i] = a2;
        sums[3] += a0; sums[4] += a1; sums[5] += a2;
    }
    __shared__ float red[256];
    for (int c = 0; c < 6; c++) {
        red[threadIdx.x] = sums[c]; __syncthreads();
        for (int off = 128; off; off >>= 1) { if (threadIdx.x < off) red[threadIdx.x] += red[threadIdx.x + off]; __syncthreads(); }
        if (threadIdx.x == 0) {
            int side = c / 3;
            ws[OFF_MEANP + ((size_t)(side * NGB + gb) * FF + f) * 3 + (c % 3)] = red[0];
        }
        __syncthreads();
    }
}

__global__ void k_meanfin(float* ws) {
    int gb = blockIdx.x, side = blockIdx.y;
    int lane = threadIdx.x;
    const float* mp = ws + OFF_MEANP + ((size_t)(side * NGB + gb) * FF) * 3;
    float s0 = mp[lane * 3], s1 = mp[lane * 3 + 1], s2 = mp[lane * 3 + 2];
#pragma unroll
    for (int off = 32; off; off >>= 1) {
        s0 += __shfl_xor(s0, off); s1 += __shfl_xor(s1, off); s2 += __shfl_xor(s2, off);
    }
    if (lane == 0) {
        float* m = ws + (side ? OFF_MEAN_A : OFF_MEAN_E) + gb * 3;
        m[0] = s0 / 65536.0f; m[1] = s1 / 65536.0f; m[2] = s2 / 65536.0f;
    }
}

// std over (n,3) of centered data, ddof=1, WITH its own mean subtraction (two-sum form)
__global__ void k_std(float* ws) {
    int gb = blockIdx.x, f = blockIdx.y, side = blockIdx.z;
    const float* M = ws + OFF_MAT + (size_t)side * MATSZ + ((size_t)gb * KF + f * 3) * NG;
    const float* mean = ws + (side ? OFF_MEAN_A : OFF_MEAN_E) + gb * 3;
    float m0 = mean[0], m1 = mean[1], m2 = mean[2];
    float s2 = 0, s1 = 0;
    for (int idx = threadIdx.x; idx < 3 * NG; idx += 128) {
        int c = idx >> 10;
        float mm = (c == 0) ? m0 : ((c == 1) ? m1 : m2);
        float v = M[idx] - mm;
        s1 += v; s2 += v * v;
    }
    __shared__ float redA[128], redB[128];
    redA[threadIdx.x] = s1; redB[threadIdx.x] = s2; __syncthreads();
    for (int off = 64; off; off >>= 1) {
        if (threadIdx.x < off) { redA[threadIdx.x] += redA[threadIdx.x + off]; redB[threadIdx.x] += redB[threadIdx.x + off]; }
        __syncthreads();
    }
    if (threadIdx.x == 0) {
        float su = redA[0], sq = redB[0];
        float var = (sq - su * su / 3072.0f) / 3071.0f;
        float* st = ws + (side ? OFF_STD_A : OFF_STD_E);
        st[gb * FF + f] = sqrtf(fmaxf(var, 0.0f));
    }
}

__global__ void k_derive(float* ws) {
    int k = blockIdx.x, gb = blockIdx.y;
    int f = k / 3, c = k % 3;
    for (int side = 0; side < 2; side++) {
        const float* P = ws + OFF_MAT + (size_t)side * MATSZ;
        float* V = ws + OFF_MAT + (size_t)(2 + side) * MATSZ;
        float* NP = ws + OFF_MAT + (size_t)(4 + side) * MATSZ;
        const float* mean = ws + (side ? OFF_MEAN_A : OFF_MEAN_E) + gb * 3;
        const float* st = ws + (side ? OFF_STD_A : OFF_STD_E) + gb * FF;
        float mm = mean[c];
        float rs = 1.0f / st[f];
        size_t base = ((size_t)gb * KF + k) * NG;
        for (int i = threadIdx.x; i < NG; i += 256) {
            float p = P[base + i];
            V[base + i] = f ? (p - P[base - 3 * NG + i]) : 0.0f;
            NP[base + i] = (p - mm) * rs;
        }
    }
}

// fallback-path norms (fp32 mats)
__global__ void k_norms(float* ws) {
    int mat = blockIdx.x, gb = blockIdx.y;
    const float* M = ws + OFF_MAT + (size_t)mat * MATSZ + (size_t)gb * KF * NG;
    float* nr = ws + OFF_NORMS + ((size_t)mat * NGB + gb) * NG;
    for (int i = threadIdx.x; i < NG; i += 256) {
        float s = 0;
        for (int k = 0; k < KF; k++) { float v = M[(size_t)k * NG + i]; s += v * v; }
        nr[i] = s;
    }
}

// transpose-convert fp32 [k][i] -> bf16 row-major [i][k] ; fold ||.||^2 partials
__global__ void k_tobf16(float* ws) {
    int x = blockIdx.x;            // 0..47: it = x&15, kt = x>>4
    int it = x & 15, kt = x >> 4;
    int gb = blockIdx.y, mat = blockIdx.z;
    const float* M = ws + OFF_MAT + (size_t)mat * MATSZ + (size_t)gb * KF * NG;
    unsigned short* out = (unsigned short*)(ws + OFF_BMAT) + ((size_t)mat * NGB + gb) * (size_t)(NG * KF);
    float* normp = ws + OFF_NORMP + ((size_t)(mat * NGB + gb) * 3 + kt) * NG;
    __shared__ float tile[64][65];
    int i0 = it * 64, k0 = kt * 64;
    int t = threadIdx.x;
    int ii = t & 63, kq = t >> 6;
#pragma unroll
    for (int rep = 0; rep < 16; rep++) {
        int kk = kq + rep * 4;
        tile[kk][ii] = M[(size_t)(k0 + kk) * NG + i0 + ii];
    }
    __syncthreads();
    int kk2 = t & 63, iq = t >> 6;
#pragma unroll
    for (int rep = 0; rep < 16; rep++) {
        int i2 = iq + rep * 4;
        float v = tile[kk2][i2];
        unsigned u = __builtin_bit_cast(unsigned, v);
        unsigned r = (u + 0x7fffu + ((u >> 16) & 1u)) >> 16;   // RNE bf16
        out[(size_t)(i0 + i2) * KF + k0 + kk2] = (unsigned short)r;
        float nsq = v * v;
#pragma unroll
        for (int off = 32; off; off >>= 1) nsq += __shfl_xor(nsq, off);
        if (kk2 == 0) normp[i0 + i2] = nsq;
    }
}

__global__ void k_normfin(float* ws) {
    int mat = blockIdx.x, gb = blockIdx.y;
    const float* np = ws + OFF_NORMP + (size_t)(mat * NGB + gb) * 3 * NG;
    float* nr = ws + OFF_NORMS + ((size_t)mat * NGB + gb) * NG;
    for (int i = threadIdx.x; i < NG; i += 256)
        nr[i] = np[i] + np[NG + i] + np[2 * NG + i];
}

// MFMA distance GEMM: 128x128 tile, 4 waves (2x2), BK=64, swizzled LDS
__global__ __launch_bounds__(256) void k_mgemm(float* ws, int cs, unsigned long long dOff) {
    int bx = blockIdx.x, by = blockIdx.y;
    int bz = blockIdx.z; int gbl = bz / 3, m3 = bz % 3;
    int gb = cs + gbl;
    int eIdx = (m3 == 0) ? 0 : ((m3 == 1) ? 4 : 2);
    int aIdx = (m3 == 0) ? 1 : ((m3 == 1) ? 5 : 3);
    const unsigned short* bmat = (const unsigned short*)(ws + OFF_BMAT);
    const unsigned short* Eg = bmat + ((size_t)eIdx * NGB + gb) * (size_t)(NG * KF);
    const unsigned short* Ag = bmat + ((size_t)aIdx * NGB + gb) * (size_t)(NG * KF);
    const float* rnE = ws + OFF_NORMS + ((size_t)eIdx * NGB + gb) * NG;
    const float* cnA = ws + OFF_NORMS + ((size_t)aIdx * NGB + gb) * NG;
    float* D = ws + dOff + ((size_t)gbl * 3 + m3) * (size_t)(NG * NG);
    int i0 = by * 128, j0 = bx * 128;
    __shared__ unsigned short lE[128 * 64];
    __shared__ unsigned short lA[128 * 64];
    int tid = threadIdx.x;
    int wid = tid >> 6, lane = tid & 63;
    int wr = wid >> 1, wc = wid & 1;
    f32x4 acc[4][4];
#pragma unroll
    for (int m = 0; m < 4; m++)
#pragma unroll
        for (int n = 0; n < 4; n++) acc[m][n] = (f32x4){0.f, 0.f, 0.f, 0.f};

    int rr = lane >> 3, ss = lane & 7;
    for (int k0 = 0; k0 < KF; k0 += 64) {
        if (k0) __syncthreads();
#pragma unroll
        for (int q = 0; q < 4; q++) {
            int r0 = wid * 32 + q * 8;
            int r = r0 + rr;
            int c = ss ^ (r & 7);
            __builtin_amdgcn_global_load_lds(
                (const __attribute__((address_space(1))) void*)(Eg + (size_t)(i0 + r) * KF + k0 + c * 8),
                (__attribute__((address_space(3))) void*)&lE[r0 * 64], 16, 0, 0);
            __builtin_amdgcn_global_load_lds(
                (const __attribute__((address_space(1))) void*)(Ag + (size_t)(j0 + r) * KF + k0 + c * 8),
                (__attribute__((address_space(3))) void*)&lA[r0 * 64], 16, 0, 0);
        }
        asm volatile("s_waitcnt vmcnt(0)" ::: "memory");
        __syncthreads();
#pragma unroll
        for (int ks = 0; ks < 2; ks++) {
            bf16x8 af[4], bfr[4];
            int kb = ks * 64 + (lane >> 4) * 16;
#pragma unroll
            for (int m = 0; m < 4; m++) {
                int arow = wr * 64 + m * 16 + (lane & 15);
                af[m] = *(const bf16x8*)((const char*)lE + arow * 128 + (kb ^ ((arow & 7) << 4)));
            }
#pragma unroll
            for (int n = 0; n < 4; n++) {
                int brow = wc * 64 + n * 16 + (lane & 15);
                bfr[n] = *(const bf16x8*)((const char*)lA + brow * 128 + (kb ^ ((brow & 7) << 4)));
            }
#pragma unroll
            for (int m = 0; m < 4; m++)
#pragma unroll
                for (int n = 0; n < 4; n++)
                    acc[m][n] = __builtin_amdgcn_mfma_f32_16x16x32_bf16(af[m], bfr[n], acc[m][n], 0, 0, 0);
        }
    }

    int colbase = j0 + wc * 64 + (lane & 15);
    int rowbase = i0 + wr * 64 + ((lane >> 4) << 2);
    float cn[4];
#pragma unroll
    for (int n = 0; n < 4; n++) cn[n] = cnA[colbase + n * 16];
#pragma unroll
    for (int m = 0; m < 4; m++) {
        int rb = rowbase + m * 16;
#pragma unroll
        for (int r = 0; r < 4; r++) {
            float rn = rnE[rb + r];
#pragma unroll
            for (int n = 0; n < 4; n++) {
                float d = rn + cn[n] - 2.0f * acc[m][n][r];
                D[(size_t)(rb + r) * NG + colbase + n * 16] = sqrtf(fmaxf(d, 1e-12f));
            }
        }
    }
}

// fallback fp32 GEMM (small-ws path)
__global__ __launch_bounds__(256) void k_gemm(float* ws, int cs) {
    int bx = blockIdx.x, by = blockIdx.y;
    int bz = blockIdx.z; int gbl = bz / 3, m = bz % 3;
    int gb = cs + gbl;
    int eIdx = (m == 0) ? 0 : ((m == 1) ? 4 : 2);
    int aIdx = (m == 0) ? 1 : ((m == 1) ? 5 : 3);
    const float* E = ws + OFF_MAT + (size_t)eIdx * MATSZ + (size_t)gb * KF * NG;
    const float* A = ws + OFF_MAT + (size_t)aIdx * MATSZ + (size_t)gb * KF * NG;
    const float* rnE = ws + OFF_NORMS + ((size_t)eIdx * NGB + gb) * NG;
    const float* cnA = ws + OFF_NORMS + ((size_t)aIdx * NGB + gb) * NG;
    float* D = ws + OFF_D + ((size_t)gbl * 3 + m) * (size_t)(NG * NG);
    int i0 = by * 128, j0 = bx * 128;
    __shared__ float4 Et[8][32], At[8][32];
    int tx = threadIdx.x, ty = threadIdx.y;
    int tid = ty * 16 + tx;
    float acc[2][2][4][4] = {};
    for (int k0 = 0; k0 < KF; k0 += 8) {
        {
            int kk = tid >> 5, i4 = tid & 31;
            Et[kk][i4] = *(const float4*)&E[(size_t)(k0 + kk) * NG + i0 + i4 * 4];
            At[kk][i4] = *(const float4*)&A[(size_t)(k0 + kk) * NG + j0 + i4 * 4];
        }
        __syncthreads();
#pragma unroll
        for (int kk = 0; kk < 8; kk++) {
            float4 e0 = Et[kk][ty], e1 = Et[kk][16 + ty];
            float4 a0 = At[kk][tx], a1 = At[kk][16 + tx];
            float er[2][4] = {{e0.x, e0.y, e0.z, e0.w}, {e1.x, e1.y, e1.z, e1.w}};
            float ar[2][4] = {{a0.x, a0.y, a0.z, a0.w}, {a1.x, a1.y, a1.z, a1.w}};
#pragma unroll
            for (int p = 0; p < 2; p++)
#pragma unroll
                for (int q = 0; q < 2; q++)
#pragma unroll
                    for (int r = 0; r < 4; r++)
#pragma unroll
                        for (int cc = 0; cc < 4; cc++)
                            acc[p][q][r][cc] += er[p][r] * ar[q][cc];
        }
        __syncthreads();
    }
    float rn[2][4], cn[2][4];
#pragma unroll
    for (int p = 0; p < 2; p++)
#pragma unroll
        for (int r = 0; r < 4; r++) rn[p][r] = rnE[i0 + p * 64 + ty * 4 + r];
#pragma unroll
    for (int q = 0; q < 2; q++)
#pragma unroll
        for (int cc = 0; cc < 4; cc++) cn[q][cc] = cnA[j0 + q * 64 + tx * 4 + cc];
#pragma unroll
    for (int p = 0; p < 2; p++)
#pragma unroll
        for (int r = 0; r < 4; r++) {
            int gi = i0 + p * 64 + ty * 4 + r;
#pragma unroll
            for (int q = 0; q < 2; q++) {
                float4 o;
                float d0 = rn[p][r] + cn[q][0] - 2.0f * acc[p][q][r][0];
                float d1 = rn[p][r] + cn[q][1] - 2.0f * acc[p][q][r][1];
                float d2_ = rn[p][r] + cn[q][2] - 2.0f * acc[p][q][r][2];
                float d3 = rn[p][r] + cn[q][3] - 2.0f * acc[p][q][r][3];
                o.x = sqrtf(fmaxf(d0, 1e-12f));
                o.y = sqrtf(fmaxf(d1, 1e-12f));
                o.z = sqrtf(fmaxf(d2_, 1e-12f));
                o.w = sqrtf(fmaxf(d3, 1e-12f));
                *(float4*)&D[(size_t)gi * NG + j0 + q * 64 + tx * 4] = o;
            }
        }
}

// per-row top-16 selection: wave per row, values held in registers
__global__ void k_select(float* ws, int cs, unsigned long long dOff) {
    int gbl = blockIdx.y; int gb = cs + gbl;
    int w = threadIdx.x >> 6, lane = threadIdx.x & 63;
    int row = blockIdx.x * 4 + w;
    const float* Dbase = ws + dOff + (size_t)gbl * 3 * (size_t)(NG * NG);
    const float* dg = Dbase + (size_t)row * NG;
    const float* dn = Dbase + (size_t)(NG * NG) + (size_t)row * NG;
    const float* dv = Dbase + (size_t)2 * (NG * NG) + (size_t)row * NG;
    float dgv[16], dnv[16], dvv[16];
#pragma unroll
    for (int q = 0; q < 16; q++) {
        dgv[q] = dg[q * 64 + lane];
        dnv[q] = dn[q * 64 + lane];
        dvv[q] = dv[q * 64 + lane];
    }
    float sg = 0, sv = 0, sn = 0;
    for (int it = 0; it < KNN; it++) {
        float best = 3.4e38f; int bc = 1 << 30;
#pragma unroll
        for (int q = 0; q < 16; q++) { float v = dgv[q]; int c = q * 64 + lane; if (v < best) { best = v; bc = c; } }
#pragma unroll
        for (int off = 32; off; off >>= 1) {
            float ov = __shfl_xor(best, off); int oc = __shfl_xor(bc, off);
            if (ov < best || (ov == best && oc < bc)) { best = ov; bc = oc; }
        }
        sg += best;
        int bq = bc >> 6, bl = bc & 63;
        float t = 0;
#pragma unroll
        for (int q = 0; q < 16; q++) if (q == bq) t = dvv[q];
        t = __shfl(t, bl); sv += t;
        if (lane == bl) {
#pragma unroll
            for (int q = 0; q < 16; q++) if (q == bq) dgv[q] = 3.4e38f;
        }
    }
    for (int it = 0; it < KNN; it++) {
        float best = 3.4e38f; int bc = 1 << 30;
#pragma unroll
        for (int q = 0; q < 16; q++) { float v = dnv[q]; int c = q * 64 + lane; if (v < best) { best = v; bc = c; } }
#pragma unroll
        for (int off = 32; off; off >>= 1) {
            float ov = __shfl_xor(best, off); int oc = __shfl_xor(bc, off);
            if (ov < best || (ov == best && oc < bc)) { best = ov; bc = oc; }
        }
        sn += best;
        int bq = bc >> 6, bl = bc & 63;
        if (lane == bl) {
#pragma unroll
            for (int q = 0; q < 16; q++) if (q == bq) dnv[q] = 3.4e38f;
        }
    }
    __shared__ float ssum[4][3];
    if (lane == 0) { ssum[w][0] = sg; ssum[w][1] = sn; ssum[w][2] = sv; }
    __syncthreads();
    if (threadIdx.x == 0) {
        float* part = ws + OFF_PART + ((size_t)gb * 256 + blockIdx.x) * 3;
        part[0] = ssum[0][0] + ssum[1][0] + ssum[2][0] + ssum[3][0];
        part[1] = ssum[0][1] + ssum[1][1] + ssum[2][1] + ssum[3][1];
        part[2] = ssum[0][2] + ssum[1][2] + ssum[2][2] + ssum[3][2];
    }
}

__global__ void k_reduce(float* ws, float* out) {
    double s[3] = {0, 0, 0};
    for (int idx = threadIdx.x; idx < 8192; idx += 256) {
        const float* p = ws + OFF_PART + (size_t)idx * 3;
        s[0] += p[0]; s[1] += p[1]; s[2] += p[2];
    }
    __shared__ double red[256];
    for (int m = 0; m < 3; m++) {
        red[threadIdx.x] = s[m]; __syncthreads();
        for (int off = 128; off; off >>= 1) { if (threadIdx.x < off) red[threadIdx.x] += red[threadIdx.x + off]; __syncthreads(); }
        if (threadIdx.x == 0) out[m] = (float)(red[0] / 524288.0 / 8.0);
        __syncthreads();
    }
}

extern "C" void kernel_launch(void* const* d_in, const int* in_sizes, int n_in,
                              void* d_out, int out_size, void* d_ws, size_t ws_size,
                              hipStream_t stream) {
    const float* ex = (const float*)d_in[0];
    const float* ac = (const float*)d_in[1];
    float* ws = (float*)d_ws;
    float* out = (float*)d_out;

    hipLaunchKernelGGL(k_bg, dim3(32), dim3(256), 0, stream, ex, ac, ws);
    hipLaunchKernelGGL(k_order, dim3(1), dim3(1024), 0, stream, ws);
    hipLaunchKernelGGL(k_gather, dim3(FF, NGB), dim3(256), 0, stream, ex, ac, ws);
    hipLaunchKernelGGL(k_meanfin, dim3(NGB, 2), dim3(64), 0, stream, ws);
    hipLaunchKernelGGL(k_std, dim3(NGB, FF, 2), dim3(128), 0, stream, ws);
    hipLaunchKernelGGL(k_derive, dim3(KF, NGB), dim3(256), 0, stream, ws);

    size_t ws_floats = ws_size / 4;
    bool fast = ws_floats >= (size_t)FAST_END;

    if (fast) {
        hipLaunchKernelGGL(k_tobf16, dim3(48, NGB, 6), dim3(256), 0, stream, ws);
        hipLaunchKernelGGL(k_normfin, dim3(6, NGB), dim3(256), 0, stream, ws);
        int gbc = 8;  // D overlays the dead fp32-mat region (6*MATSZ = exactly 8*3*NG*NG)
        for (int cs = 0; cs < NGB; cs += gbc) {
            int take = (NGB - cs < gbc) ? (NGB - cs) : gbc;
            hipLaunchKernelGGL(k_mgemm, dim3(8, 8, take * 3), dim3(256), 0, stream, ws, cs, (unsigned long long)OFF_MAT);
            hipLaunchKernelGGL(k_select, dim3(256, take), dim3(256), 0, stream, ws, cs, (unsigned long long)OFF_MAT);
        }
    } else {
        hipLaunchKernelGGL(k_norms, dim3(6, NGB), dim3(256), 0, stream, ws);
        size_t dcap = (ws_floats > (size_t)OFF_D) ? (ws_floats - (size_t)OFF_D) : 0;
        int gbc = (int)(dcap / (3ull * NG * NG));
        if (gbc < 1) gbc = 1;
        if (gbc > 32) gbc = 32;
        for (int cs = 0; cs < NGB; cs += gbc) {
            int take = (NGB - cs < gbc) ? (NGB - cs) : gbc;
            hipLaunchKernelGGL(k_gemm, dim3(8, 8, take * 3), dim3(16, 16), 0, stream, ws, cs);
            hipLaunchKernelGGL(k_select, dim3(256, take), dim3(256), 0, stream, ws, cs, (unsigned long long)OFF_D);
        }
    }
    hipLaunchKernelGGL(k_reduce, dim3(1), dim3(256), 0, stream, ws, out);
}